// Round 8
// baseline (100.477 us; speedup 1.0000x reference)
//
#include <hip/hip_runtime.h>
#include <math.h>
#include <stdint.h>

#define IN_DIM  256
#define OUT_DIM 256
#define NROWS   68     // G + K
#define NT      71     // knot count
#define BATCH   512
#define W_ELEMS (NROWS * IN_DIM * OUT_DIM)   // 4,456,448
#define NCG     16                            // channel groups of 16
#define PART_FLOATS (NCG * BATCH * OUT_DIM)   // 2,097,152 floats = 8 MB

// ---- Kernel A: convert w fp32 -> packed bf16 pairs (streaming) ----
__device__ __forceinline__ uint32_t bf16_rne(float f) {
  uint32_t u = __builtin_bit_cast(uint32_t, f);
  return (u + 0x7fffu + ((u >> 16) & 1u)) >> 16;   // finite inputs only
}

__global__ __launch_bounds__(256) void cvt_kernel(const float* __restrict__ w,
                                                  uint32_t* __restrict__ wb) {
  const int base = (blockIdx.x * 256 + threadIdx.x) * 8;   // 8 floats / thread
  const float4 a = *(const float4*)(w + base);
  const float4 b = *(const float4*)(w + base + 4);
  uint4 o;
  o.x = bf16_rne(a.x) | (bf16_rne(a.y) << 16);
  o.y = bf16_rne(a.z) | (bf16_rne(a.w) << 16);
  o.z = bf16_rne(b.x) | (bf16_rne(b.y) << 16);
  o.w = bf16_rne(b.z) | (bf16_rne(b.w) << 16);
  *(uint4*)(wb + base / 2) = o;
}

// ---- Kernel B: LDS-staged gather. Block = 32 b x 16 channels, grid 256
//      (16 bgroups x 16 cgroups, 1 block/CU). Per channel: stage ALL 68
//      rows once into LDS (global_load_lds, 34 dual-row wave-instrs), then
//      the 32 b's read their 4+1 rows via ds_read_b128 (never-miss LDS
//      pipe ~6.4 us/CU floor) instead of 655K scattered global loads.
//      No cross-wave reduction: each (b, o-octet) owned by one thread. ----
__device__ __forceinline__ void fma8(const uint4 q, const float y, float* acc) {
  acc[0] += y * __builtin_bit_cast(float, q.x << 16);
  acc[1] += y * __builtin_bit_cast(float, q.x & 0xffff0000u);
  acc[2] += y * __builtin_bit_cast(float, q.y << 16);
  acc[3] += y * __builtin_bit_cast(float, q.y & 0xffff0000u);
  acc[4] += y * __builtin_bit_cast(float, q.z << 16);
  acc[5] += y * __builtin_bit_cast(float, q.z & 0xffff0000u);
  acc[6] += y * __builtin_bit_cast(float, q.w << 16);
  acc[7] += y * __builtin_bit_cast(float, q.w & 0xffff0000u);
}

__global__ __launch_bounds__(256) void kan_gather_kernel(
    const float* __restrict__ x, const uint4* __restrict__ wp,
    const float* __restrict__ t, float* __restrict__ part) {
  __shared__ float  lt[NT];
  __shared__ float4 nA[16][32];        // N0..N3 per (local c, local b)
  __shared__ float  sA[16][32];        // silu(x)
  __shared__ int    bA[16][32];        // base row (i-3)
  __shared__ uint4  lbuf[NROWS * 32];  // one channel: 68 rows x 512 B = 34 KB

  const int tid = threadIdx.x;
  const unsigned bid = blockIdx.x;
  // cgroup in the low 4 bits: bid%8 == cg%8, so the 16 bgroup-blocks of
  // cgroups {x, x+8} share XCD x -> 1.1 MB distinct weights per XCD L2.
  const int cg     = bid & 15;
  const int bgroup = bid >> 4;         // 16 groups of 32 batch rows

  if (tid < NT) lt[tid] = t[tid];
  __syncthreads();

  // ---- Phase 1: basis for 32 b x 16 c; two (b,c) pairs per thread ----
  for (int p = tid; p < 512; p += 256) {
    const int cl = p >> 5;             // local channel 0..15
    const int bb = p & 31;             // local batch row 0..31
    const float xv = x[(size_t)(bgroup * 32 + bb) * IN_DIM + cg * 16 + cl];
    int i = 3 + (int)floorf((xv + 1.0f) * 32.0f);
    i = i < 3 ? 3 : (i > 66 ? 66 : i);
    while (i > 3 && xv < lt[i]) --i;
    while (i < 66 && xv >= lt[i + 1]) ++i;

    float N0 = 1.f, N1 = 0.f, N2 = 0.f, N3 = 0.f;
    { // p = 1
      const float l1 = xv - lt[i];
      const float r1 = lt[i + 1] - xv;
      const float tp = N0 / (r1 + l1);
      N1 = l1 * tp; N0 = r1 * tp;
    }
    { // p = 2
      const float l1 = xv - lt[i];
      const float l2 = xv - lt[i - 1];
      const float r1 = lt[i + 1] - xv;
      const float r2 = lt[i + 2] - xv;
      float saved = 0.f;
      const float tp0 = N0 / (r1 + l2);
      const float n0 = saved + r1 * tp0; saved = l2 * tp0;
      const float tp1 = N1 / (r2 + l1);
      const float n1 = saved + r2 * tp1; saved = l1 * tp1;
      N0 = n0; N1 = n1; N2 = saved;
    }
    { // p = 3
      const float l1 = xv - lt[i];
      const float l2 = xv - lt[i - 1];
      const float l3 = xv - lt[i - 2];
      const float r1 = lt[i + 1] - xv;
      const float r2 = lt[i + 2] - xv;
      const float r3 = lt[i + 3] - xv;
      float saved = 0.f;
      const float tp0 = N0 / (r1 + l3);
      const float n0 = saved + r1 * tp0; saved = l3 * tp0;
      const float tp1 = N1 / (r2 + l2);
      const float n1 = saved + r2 * tp1; saved = l2 * tp1;
      const float tp2 = N2 / (r3 + l1);
      const float n2 = saved + r3 * tp2; saved = l1 * tp2;
      N0 = n0; N1 = n1; N2 = n2; N3 = saved;
    }
    nA[cl][bb] = make_float4(N0, N1, N2, N3);
    sA[cl][bb] = xv / (1.0f + expf(-xv));
    bA[cl][bb] = i - 3;
  }
  __syncthreads();

  // ---- Phase 2: per channel: stage 68 rows -> LDS, then gather from LDS.
  //      Wave wv owns b's [wv*8, wv*8+8): per pass 2 b's (half-wave each,
  //      32 lanes x uint4 = full 256-o bf16 row). ----
  const int wv   = tid >> 6;
  const int lane = tid & 63;
  const int half = lane >> 5;
  const int ol   = lane & 31;          // uint4 (8-o) slot: o = ol*8 + j

  float acc[4][8];
  #pragma unroll
  for (int bp = 0; bp < 4; ++bp) {
    #pragma unroll
    for (int j = 0; j < 8; ++j) acc[bp][j] = 0.f;
  }

  for (int ch = 0; ch < 16; ++ch) {
    // stage channel ch: 34 dual-row instrs round-robined over the 4 waves;
    // LDS dest = wave-uniform base + lane*16 (global src is per-lane).
    {
      const uint32_t cb = (uint32_t)(cg * 16 + ch) * 32;
      for (int i = wv; i < 34; i += 4) {
        const int Xu = i * 64 + lane;          // uint4 index in tile
        const int r  = Xu >> 5;                // row = 2i or 2i+1
        const int off = Xu & 31;
        const uint4* src = wp + ((uint32_t)r << 13) + cb + off;
        __builtin_amdgcn_global_load_lds((const uint32_t*)src,
                                         (uint32_t*)&lbuf[i * 64], 16, 0, 0);
      }
    }
    __syncthreads();   // drains vmcnt -> staged rows visible

    const uint4 q4 = lbuf[67 * 32 + ol];       // silu row, once per channel
    #pragma unroll
    for (int bp = 0; bp < 4; ++bp) {
      const int bb = wv * 8 + bp * 2 + half;
      const float4 yv = nA[ch][bb];
      const float  ys = sA[ch][bb];
      const int    rb = bA[ch][bb] * 32 + ol;
      const uint4 q0 = lbuf[rb];
      const uint4 q1 = lbuf[rb + 32];
      const uint4 q2 = lbuf[rb + 64];
      const uint4 q3 = lbuf[rb + 96];
      fma8(q0, yv.x, acc[bp]);
      fma8(q1, yv.y, acc[bp]);
      fma8(q2, yv.z, acc[bp]);
      fma8(q3, yv.w, acc[bp]);
      fma8(q4, ys,   acc[bp]);
    }
    __syncthreads();   // all waves done reading before next stage overwrites
  }

  // ---- Phase 3: direct store; each (b, o-octet) owned by one thread ----
  {
    float* dst = part + ((size_t)cg * BATCH + bgroup * 32) * OUT_DIM;
    #pragma unroll
    for (int bp = 0; bp < 4; ++bp) {
      const int bb = wv * 8 + bp * 2 + half;
      float* d = dst + (size_t)bb * OUT_DIM + ol * 8;
      *(float4*)d       = make_float4(acc[bp][0], acc[bp][1], acc[bp][2], acc[bp][3]);
      *(float4*)(d + 4) = make_float4(acc[bp][4], acc[bp][5], acc[bp][6], acc[bp][7]);
    }
  }
}

// ---- Kernel C: reduce the 16 c-group partials into out ----
__global__ __launch_bounds__(256) void reduce_kernel(const float* __restrict__ part,
                                                     float* __restrict__ out) {
  const int q = blockIdx.x * 256 + threadIdx.x;   // float4 index, 32768 total
  const int S = BATCH * OUT_DIM / 4;              // float4 stride per slice
  const float4* p = (const float4*)part;
  float4 s = p[q];
  #pragma unroll
  for (int k = 1; k < NCG; ++k) {
    const float4 a = p[q + k * S];
    s.x += a.x; s.y += a.y; s.z += a.z; s.w += a.w;
  }
  ((float4*)out)[q] = s;
}

extern "C" void kernel_launch(void* const* d_in, const int* in_sizes, int n_in,
                              void* d_out, int out_size, void* d_ws, size_t ws_size,
                              hipStream_t stream) {
  const float* x = (const float*)d_in[0];
  const float* w = (const float*)d_in[1];
  const float* t = (const float*)d_in[2];
  float* out  = (float*)d_out;
  float* part = (float*)d_ws;                       // 8 MB of partials
  uint32_t* wb = (uint32_t*)d_ws + PART_FLOATS;     // bf16 weights after
  cvt_kernel<<<W_ELEMS / (256 * 8), 256, 0, stream>>>(w, wb);
  kan_gather_kernel<<<256, 256, 0, stream>>>(x, (const uint4*)wb, t, part);
  reduce_kernel<<<BATCH * OUT_DIM / 4 / 256, 256, 0, stream>>>(part, out);
}

// Round 9
// 94.072 us; speedup vs baseline: 1.0681x; 1.0681x over previous
//
#include <hip/hip_runtime.h>
#include <math.h>
#include <stdint.h>

#define IN_DIM  256
#define OUT_DIM 256
#define NROWS   68     // G + K
#define NT      71     // knot count
#define BATCH   512
#define W_ELEMS (NROWS * IN_DIM * OUT_DIM)   // 4,456,448
#define NCG     32                            // channel groups of 8
#define PART_FLOATS (NCG * BATCH * OUT_DIM)   // 4,194,304 floats = 16 MB

// ---- Kernel A: convert w fp32 -> packed bf16 pairs (streaming) ----
__device__ __forceinline__ uint32_t bf16_rne(float f) {
  uint32_t u = __builtin_bit_cast(uint32_t, f);
  return (u + 0x7fffu + ((u >> 16) & 1u)) >> 16;   // finite inputs only
}

__global__ __launch_bounds__(256) void cvt_kernel(const float* __restrict__ w,
                                                  uint32_t* __restrict__ wb) {
  const int base = (blockIdx.x * 256 + threadIdx.x) * 8;   // 8 floats / thread
  const float4 a = *(const float4*)(w + base);
  const float4 b = *(const float4*)(w + base + 4);
  uint4 o;
  o.x = bf16_rne(a.x) | (bf16_rne(a.y) << 16);
  o.y = bf16_rne(a.z) | (bf16_rne(a.w) << 16);
  o.z = bf16_rne(b.x) | (bf16_rne(b.y) << 16);
  o.w = bf16_rne(b.z) | (bf16_rne(b.w) << 16);
  *(uint4*)(wb + base / 2) = o;
}

// ---- Kernel B: bf16 gather-accumulate.
//      Block = 32 b x 8 channels, grid 512 (2 blocks/CU, 8 waves/CU).
//      All 4 waves process the SAME channel simultaneously (phase-locked by
//      a per-channel barrier): 32-b row-window union ~57 of 68 rows, so the
//      waves' overlapping requests merge in L1/MSHR -> L2 line traffic
//      ~119 MB vs R1's ~218 MB. Direct global loads (no LDS staging, no
//      single-buffer serialization); each thread owns (b, o-octet) fully,
//      so there is NO cross-wave reduction at all. ----
__device__ __forceinline__ void fma8(const uint4 q, const float y, float* acc) {
  acc[0] += y * __builtin_bit_cast(float, q.x << 16);
  acc[1] += y * __builtin_bit_cast(float, q.x & 0xffff0000u);
  acc[2] += y * __builtin_bit_cast(float, q.y << 16);
  acc[3] += y * __builtin_bit_cast(float, q.y & 0xffff0000u);
  acc[4] += y * __builtin_bit_cast(float, q.z << 16);
  acc[5] += y * __builtin_bit_cast(float, q.z & 0xffff0000u);
  acc[6] += y * __builtin_bit_cast(float, q.w << 16);
  acc[7] += y * __builtin_bit_cast(float, q.w & 0xffff0000u);
}

__global__ __launch_bounds__(256) void kan_gather_kernel(
    const float* __restrict__ x, const uint4* __restrict__ wp,
    const float* __restrict__ t, float* __restrict__ part) {
  __shared__ float  lt[NT];
  __shared__ float4 nA[8][32];   // N0..N3 per (local c, local b)
  __shared__ float  sA[8][32];   // silu(x)
  __shared__ int    bA[8][32];   // base row (i-3)

  const int tid = threadIdx.x;
  const unsigned bid = blockIdx.x;
  // cg = bid&31 -> 32 cgroups of 8 channels. Dispatch round-robins bid%8
  // across XCDs, so cgroups with cg%8==x land on XCD x: per-XCD distinct
  // weights = 4 cgroups * 8 ch * 68 rows * 512 B = 1.1 MB (L2-resident).
  const int cg     = bid & 31;
  const int bgroup = bid >> 5;   // 16 groups of 32 batch rows

  if (tid < NT) lt[tid] = t[tid];
  __syncthreads();

  // ---- Phase 1: basis for 32 b x 8 c; exactly one (b,c) pair per thread ----
  {
    const int cl = tid & 7;
    const int bb = tid >> 3;
    const float xv = x[(size_t)(bgroup * 32 + bb) * IN_DIM + cg * 8 + cl];
    int i = 3 + (int)floorf((xv + 1.0f) * 32.0f);
    i = i < 3 ? 3 : (i > 66 ? 66 : i);
    while (i > 3 && xv < lt[i]) --i;
    while (i < 66 && xv >= lt[i + 1]) ++i;

    float N0 = 1.f, N1 = 0.f, N2 = 0.f, N3 = 0.f;
    { // p = 1
      const float l1 = xv - lt[i];
      const float r1 = lt[i + 1] - xv;
      const float tp = N0 / (r1 + l1);
      N1 = l1 * tp; N0 = r1 * tp;
    }
    { // p = 2
      const float l1 = xv - lt[i];
      const float l2 = xv - lt[i - 1];
      const float r1 = lt[i + 1] - xv;
      const float r2 = lt[i + 2] - xv;
      float saved = 0.f;
      const float tp0 = N0 / (r1 + l2);
      const float n0 = saved + r1 * tp0; saved = l2 * tp0;
      const float tp1 = N1 / (r2 + l1);
      const float n1 = saved + r2 * tp1; saved = l1 * tp1;
      N0 = n0; N1 = n1; N2 = saved;
    }
    { // p = 3
      const float l1 = xv - lt[i];
      const float l2 = xv - lt[i - 1];
      const float l3 = xv - lt[i - 2];
      const float r1 = lt[i + 1] - xv;
      const float r2 = lt[i + 2] - xv;
      const float r3 = lt[i + 3] - xv;
      float saved = 0.f;
      const float tp0 = N0 / (r1 + l3);
      const float n0 = saved + r1 * tp0; saved = l3 * tp0;
      const float tp1 = N1 / (r2 + l2);
      const float n1 = saved + r2 * tp1; saved = l2 * tp1;
      const float tp2 = N2 / (r3 + l1);
      const float n2 = saved + r3 * tp2; saved = l1 * tp2;
      N0 = n0; N1 = n1; N2 = n2; N3 = saved;
    }
    nA[cl][bb] = make_float4(N0, N1, N2, N3);
    sA[cl][bb] = xv / (1.0f + expf(-xv));
    bA[cl][bb] = i - 3;
  }
  __syncthreads();

  // ---- Phase 2: loop channels; wave owns 8 b's (pass p: b = wv*8+p*2+half,
  //      half-wave = 32 lanes x uint4 = full 256-o bf16 row). Batch-issue
  //      all 17 loads of the channel, then all FMAs (R7's proven pattern). ----
  const int wv   = tid >> 6;
  const int lane = tid & 63;
  const int half = lane >> 5;
  const int ol   = lane & 31;     // uint4 (8-o) slot: o = ol*8 + j

  float acc[4][8];
  #pragma unroll
  for (int p = 0; p < 4; ++p) {
    #pragma unroll
    for (int j = 0; j < 8; ++j) acc[p][j] = 0.f;
  }

  for (int ch = 0; ch < 8; ++ch) {
    const uint32_t cbase = (uint32_t)((cg * 8 + ch) * 32 + ol);
    const uint4 q4 = wp[cbase + 67u * 8192u];   // silu row (halves share lines)

    uint4 q[4][4];
    #pragma unroll
    for (int p = 0; p < 4; ++p) {
      const int bb = wv * 8 + p * 2 + half;
      const uint32_t rb = cbase + ((uint32_t)bA[ch][bb] << 13);
      q[p][0] = wp[rb];
      q[p][1] = wp[rb +  8192u];
      q[p][2] = wp[rb + 16384u];
      q[p][3] = wp[rb + 24576u];
    }
    #pragma unroll
    for (int p = 0; p < 4; ++p) {
      const int bb = wv * 8 + p * 2 + half;
      const float4 yv = nA[ch][bb];
      const float  ys = sA[ch][bb];
      fma8(q[p][0], yv.x, acc[p]);
      fma8(q[p][1], yv.y, acc[p]);
      fma8(q[p][2], yv.z, acc[p]);
      fma8(q[p][3], yv.w, acc[p]);
      fma8(q4,      ys,   acc[p]);
    }
    __syncthreads();   // phase-lock waves on the channel -> L1/MSHR sharing
  }

  // ---- Phase 3: direct store; thread owns (b, o-octet), no reduction ----
  {
    float* dst0 = part + ((size_t)cg * BATCH + bgroup * 32) * OUT_DIM;
    #pragma unroll
    for (int p = 0; p < 4; ++p) {
      const int bb = wv * 8 + p * 2 + half;
      float* d = dst0 + (size_t)bb * OUT_DIM + ol * 8;
      *(float4*)d       = make_float4(acc[p][0], acc[p][1], acc[p][2], acc[p][3]);
      *(float4*)(d + 4) = make_float4(acc[p][4], acc[p][5], acc[p][6], acc[p][7]);
    }
  }
}

// ---- Kernel C: reduce the 32 c-group partials into out ----
__global__ __launch_bounds__(256) void reduce_kernel(const float* __restrict__ part,
                                                     float* __restrict__ out) {
  const int q = blockIdx.x * 256 + threadIdx.x;   // float4 index, 32768 total
  const int S = BATCH * OUT_DIM / 4;              // float4 stride per slice
  const float4* p = (const float4*)part;
  float4 s = p[q];
  #pragma unroll
  for (int k = 1; k < NCG; ++k) {
    const float4 a = p[q + k * S];
    s.x += a.x; s.y += a.y; s.z += a.z; s.w += a.w;
  }
  ((float4*)out)[q] = s;
}

extern "C" void kernel_launch(void* const* d_in, const int* in_sizes, int n_in,
                              void* d_out, int out_size, void* d_ws, size_t ws_size,
                              hipStream_t stream) {
  const float* x = (const float*)d_in[0];
  const float* w = (const float*)d_in[1];
  const float* t = (const float*)d_in[2];
  float* out  = (float*)d_out;
  float* part = (float*)d_ws;                       // 16 MB of partials
  uint32_t* wb = (uint32_t*)d_ws + PART_FLOATS;     // bf16 weights after
  cvt_kernel<<<W_ELEMS / (256 * 8), 256, 0, stream>>>(w, wb);
  kan_gather_kernel<<<512, 256, 0, stream>>>(x, (const uint4*)wb, t, part);
  reduce_kernel<<<BATCH * OUT_DIM / 4 / 256, 256, 0, stream>>>(part, out);
}